// Round 3
// baseline (59.092 us; speedup 1.0000x reference)
//
#include <hip/hip_runtime.h>
#include <hip/hip_bf16.h>
#include <math.h>

// DDRFMixer: out[b,t,d] = sum_n softmax_n(x[b,t,:]·W[n,:]) * x[b,t-off_n,d]
// x: [B,T,D] fp32, W: [7,D] fp32, out: [B,T,D] fp32
// B=4, T=4096, D=1024, offsets = {1,2,4,8,16,32,64}

#define N_TAPS 7
#define DIM 1024

__constant__ int c_offs[N_TAPS] = {1, 2, 4, 8, 16, 32, 64};

__global__ __launch_bounds__(256) void ddrf_mixer_kernel(
    const float* __restrict__ x,   // [B*T, D]
    const float* __restrict__ W,   // [N_TAPS, D]
    float* __restrict__ out,       // [B*T, D]
    int T)
{
    const int row  = blockIdx.x;          // b*T + t
    const int t    = row & (T - 1);       // T = 4096 (power of 2)
    const int j    = threadIdx.x;         // 0..255, owns d = 4j..4j+3
    const int lane = j & 63;
    const int wave = j >> 6;

    const size_t rbase = (size_t)row * DIM + 4 * j;

    // ---- Phase 1: logits_n = x[row,:] . W[n,:] ----
    const float4 xv = *reinterpret_cast<const float4*>(x + rbase);

    float p[N_TAPS];
#pragma unroll
    for (int n = 0; n < N_TAPS; ++n) {
        const float4 wv = *reinterpret_cast<const float4*>(W + n * DIM + 4 * j);
        p[n] = xv.x * wv.x + xv.y * wv.y + xv.z * wv.z + xv.w * wv.w;
    }

    // wave-level butterfly reduce (64 lanes)
#pragma unroll
    for (int n = 0; n < N_TAPS; ++n) {
#pragma unroll
        for (int m = 32; m >= 1; m >>= 1) {
            p[n] += __shfl_xor(p[n], m, 64);
        }
    }

    // combine 4 waves via LDS
    __shared__ float red[4][N_TAPS];
    if (lane == 0) {
#pragma unroll
        for (int n = 0; n < N_TAPS; ++n) red[wave][n] = p[n];
    }
    __syncthreads();

    float logit[N_TAPS];
    float mx = -INFINITY;
#pragma unroll
    for (int n = 0; n < N_TAPS; ++n) {
        logit[n] = red[0][n] + red[1][n] + red[2][n] + red[3][n];
        mx = fmaxf(mx, logit[n]);
    }

    float wn[N_TAPS];
    float wsum = 0.0f;
#pragma unroll
    for (int n = 0; n < N_TAPS; ++n) {
        wn[n] = __expf(logit[n] - mx);
        wsum += wn[n];
    }
    const float inv = 1.0f / wsum;

    // ---- Phase 2: out = sum_n w_n * x[row - off_n, d] (causal: 0 if t < off_n) ----
    float4 acc = make_float4(0.f, 0.f, 0.f, 0.f);
#pragma unroll
    for (int n = 0; n < N_TAPS; ++n) {
        const int off = c_offs[n];
        if (t >= off) {  // wave-uniform branch (t is uniform across the block)
            const float4 tv =
                *reinterpret_cast<const float4*>(x + rbase - (size_t)off * DIM);
            const float w = wn[n] * inv;
            acc.x = fmaf(w, tv.x, acc.x);
            acc.y = fmaf(w, tv.y, acc.y);
            acc.z = fmaf(w, tv.z, acc.z);
            acc.w = fmaf(w, tv.w, acc.w);
        }
    }

    *reinterpret_cast<float4*>(out + rbase) = acc;
}

extern "C" void kernel_launch(void* const* d_in, const int* in_sizes, int n_in,
                              void* d_out, int out_size, void* d_ws, size_t ws_size,
                              hipStream_t stream) {
    const float* x = (const float*)d_in[0];   // [B,T,D] fp32
    const float* W = (const float*)d_in[1];   // [N_TAPS,D] fp32
    float* out = (float*)d_out;               // [B,T,D] fp32

    const int T = 4096;
    const int n_rows = in_sizes[0] / DIM;     // B*T = 16384

    ddrf_mixer_kernel<<<n_rows, 256, 0, stream>>>(x, W, out, T);
}

// Round 4
// 42.522 us; speedup vs baseline: 1.3897x; 1.3897x over previous
//
#include <hip/hip_runtime.h>
#include <hip/hip_bf16.h>
#include <math.h>

// DDRFMixer: out[b,t,d] = sum_n softmax_n(x[b,t,:]·W[n,:]) * x[b,t-off_n,d]
// x: [B,T,D] fp32, W: [7,D] fp32, out: [B,T,D] fp32
// B=4, T=4096, D=1024, offsets = {1,2,4,8,16,32,64}
//
// Structure: ONE WAVE PER ROW (no __syncthreads, no LDS). Lane owns
// d = k*256 + lane*4 for k=0..3 (each float4 load across the wave is a
// contiguous 1024B segment). XCD-aware block swizzle so each XCD's L2
// holds a contiguous 2048-row chunk -> tap reads (offsets <= 64 rows,
// 256 KB window) are local-L2 hits instead of cross-XCD misses.

#define N_TAPS 7
#define DIM 1024
#define T_LEN 4096
#define NXCD 8

__global__ __launch_bounds__(256) void ddrf_mixer_kernel(
    const float* __restrict__ x,   // [B*T, D]
    const float* __restrict__ W,   // [N_TAPS, D]
    float* __restrict__ out,       // [B*T, D]
    int n_rows)
{
    constexpr int offs[N_TAPS] = {1, 2, 4, 8, 16, 32, 64};

    // Bijective XCD swizzle (gridDim.x % 8 == 0): XCD i gets a contiguous
    // chunk of the row space -> tap window stays in the local 4 MiB L2.
    const int per = gridDim.x >> 3;
    const int wg  = (blockIdx.x & (NXCD - 1)) * per + (blockIdx.x >> 3);

    const int wave = threadIdx.x >> 6;
    const int lane = threadIdx.x & 63;
    const int row  = wg * 4 + wave;          // one wave per row
    if (row >= n_rows) return;
    const int t = row & (T_LEN - 1);

    const float* xrow = x + (size_t)row * DIM;
    const int    dofs = lane * 4;            // lane's base within each 256-chunk

    // ---- load this row's 16 elements (4 strided float4) ----
    float4 xv[4];
#pragma unroll
    for (int k = 0; k < 4; ++k)
        xv[k] = *reinterpret_cast<const float4*>(xrow + k * 256 + dofs);

    // ---- Phase 1: partial dots x[row,:] . W[n,:] ----
    float p[N_TAPS];
#pragma unroll
    for (int n = 0; n < N_TAPS; ++n) {
        const float* wrow = W + n * DIM;
        float s0 = 0.f, s1 = 0.f, s2 = 0.f, s3 = 0.f;
        float4 w0 = *reinterpret_cast<const float4*>(wrow + 0 * 256 + dofs);
        float4 w1 = *reinterpret_cast<const float4*>(wrow + 1 * 256 + dofs);
        float4 w2 = *reinterpret_cast<const float4*>(wrow + 2 * 256 + dofs);
        float4 w3 = *reinterpret_cast<const float4*>(wrow + 3 * 256 + dofs);
        s0 = fmaf(xv[0].x, w0.x, fmaf(xv[0].y, w0.y, fmaf(xv[0].z, w0.z, xv[0].w * w0.w)));
        s1 = fmaf(xv[1].x, w1.x, fmaf(xv[1].y, w1.y, fmaf(xv[1].z, w1.z, xv[1].w * w1.w)));
        s2 = fmaf(xv[2].x, w2.x, fmaf(xv[2].y, w2.y, fmaf(xv[2].z, w2.z, xv[2].w * w2.w)));
        s3 = fmaf(xv[3].x, w3.x, fmaf(xv[3].y, w3.y, fmaf(xv[3].z, w3.z, xv[3].w * w3.w)));
        p[n] = (s0 + s1) + (s2 + s3);
    }

    // ---- wave-level butterfly reduce (64 lanes), all 7 taps ----
#pragma unroll
    for (int n = 0; n < N_TAPS; ++n) {
#pragma unroll
        for (int m = 32; m >= 1; m >>= 1)
            p[n] += __shfl_xor(p[n], m, 64);
    }

    // ---- softmax over 7 taps (redundant per lane, cheap) ----
    float mx = p[0];
#pragma unroll
    for (int n = 1; n < N_TAPS; ++n) mx = fmaxf(mx, p[n]);
    float wn[N_TAPS];
    float wsum = 0.f;
#pragma unroll
    for (int n = 0; n < N_TAPS; ++n) {
        wn[n] = __expf(p[n] - mx);
        wsum += wn[n];
    }
    const float inv = 1.0f / wsum;

    // ---- Phase 2: weighted sum of past taps ----
    float4 acc[4];
#pragma unroll
    for (int k = 0; k < 4; ++k) acc[k] = make_float4(0.f, 0.f, 0.f, 0.f);

#pragma unroll
    for (int n = 0; n < N_TAPS; ++n) {
        const int off = offs[n];
        if (t >= off) {                       // wave-uniform branch
            const float* trow = xrow - (size_t)off * DIM;
            const float w = wn[n] * inv;
#pragma unroll
            for (int k = 0; k < 4; ++k) {
                const float4 tv =
                    *reinterpret_cast<const float4*>(trow + k * 256 + dofs);
                acc[k].x = fmaf(w, tv.x, acc[k].x);
                acc[k].y = fmaf(w, tv.y, acc[k].y);
                acc[k].z = fmaf(w, tv.z, acc[k].z);
                acc[k].w = fmaf(w, tv.w, acc[k].w);
            }
        }
    }

    float* orow = out + (size_t)row * DIM;
#pragma unroll
    for (int k = 0; k < 4; ++k)
        *reinterpret_cast<float4*>(orow + k * 256 + dofs) = acc[k];
}

extern "C" void kernel_launch(void* const* d_in, const int* in_sizes, int n_in,
                              void* d_out, int out_size, void* d_ws, size_t ws_size,
                              hipStream_t stream) {
    const float* x = (const float*)d_in[0];   // [B,T,D] fp32
    const float* W = (const float*)d_in[1];   // [N_TAPS,D] fp32
    float* out = (float*)d_out;               // [B,T,D] fp32

    const int n_rows = in_sizes[0] / DIM;     // B*T = 16384
    const int n_blocks = n_rows / 4;          // 4096, divisible by 8 (XCD swizzle)

    ddrf_mixer_kernel<<<n_blocks, 256, 0, stream>>>(x, W, out, n_rows);
}